// Round 2
// baseline (279.179 us; speedup 1.0000x reference)
//
#include <hip/hip_runtime.h>
#include <hip/hip_bf16.h>

#define BB   32768
#define LL   1024
#define FEA  1028
#define MEM  50
#define DATE 32

typedef float  f32x4  __attribute__((ext_vector_type(4)));
typedef __bf16 bf16x8 __attribute__((ext_vector_type(8)));

__device__ __forceinline__ float wave_max(float v) {
    #pragma unroll
    for (int off = 32; off; off >>= 1) v = fmaxf(v, __shfl_xor(v, off));
    return v;
}
__device__ __forceinline__ float wave_sum(float v) {
    #pragma unroll
    for (int off = 32; off; off >>= 1) v += __shfl_xor(v, off);
    return v;
}

// K1: fold transposed-conv into the memory matrix (all f32 in, bf16 out for MFMA B).
// wc[i*64+k] = Wc_T[i][k] = sum_j convt_w[j] * mem_W[k][i+4-j], zero for k>=50.
__global__ void prep_wc(const float* __restrict__ convt_w,
                        const float* __restrict__ mem_W,
                        __bf16* __restrict__ wc) {
    int idx = blockIdx.x * 256 + threadIdx.x;   // 65536 total
    int i = idx >> 6, k = idx & 63;
    float acc = 0.f;
    if (k < MEM) {
        #pragma unroll
        for (int j = 0; j < 5; ++j)
            acc += convt_w[j] * mem_W[k * FEA + i + 4 - j];
    }
    wc[i * 64 + k] = (__bf16)acc;
}

// K2: 32 rows per block, 256 threads (4 waves).
__global__ __launch_bounds__(256) void memconv_main(
        const float* __restrict__ x,
        const float* __restrict__ dv,
        const float* __restrict__ dW,
        const float* __restrict__ fcw_w, const float* __restrict__ fcw_b,
        const float* __restrict__ fcb_w, const float* __restrict__ fcb_b,
        const __bf16* __restrict__ wc,
        float* __restrict__ out) {
    __shared__ __bf16 att_s[32 * 72];   // [row][k], stride 72
    __shared__ float  w_s[32], b_s[32];

    const int tid  = threadIdx.x;
    const int lane = tid & 63;
    const int wid  = tid >> 6;
    const int b0   = blockIdx.x * 32;

    // ---- Phase 1: att for this block's 32 rows (8 per wave); store bf16 to LDS ----
    {
        int m = lane < MEM ? lane : MEM - 1;
        float dwv[DATE];
        const f32x4* dwp = (const f32x4*)(dW + m * DATE);
        #pragma unroll
        for (int c = 0; c < 8; ++c) {
            f32x4 v = dwp[c];
            #pragma unroll
            for (int j = 0; j < 4; ++j) dwv[c * 4 + j] = v[j];
        }
        for (int rr = 0; rr < 8; ++rr) {
            int r = wid * 8 + rr;
            int b = b0 + r;
            const f32x4* dvp = (const f32x4*)(dv + (size_t)b * DATE);
            float sc = 0.f;
            #pragma unroll
            for (int c = 0; c < 8; ++c) {
                f32x4 v = dvp[c];
                #pragma unroll
                for (int j = 0; j < 4; ++j) sc += v[j] * dwv[c * 4 + j];
            }
            float scm = (lane < MEM) ? sc : -1e30f;
            float mx  = wave_max(scm);
            float e   = (lane < MEM) ? __expf(sc - mx) : 0.f;
            float s   = wave_sum(e);
            float p   = e / s;                       // softmax
            float d   = p - 0.0025f;                 // SHRINK
            float p2  = (d > 0.f) ? p * d / (d + 1e-12f) : 0.f;
            float s2  = wave_sum(p2) + 1e-12f;
            float att = p2 / s2;
            att_s[r * 72 + lane] = (lane < MEM) ? (__bf16)att : (__bf16)0.f;
        }
    }

    // ---- Phase 2: weight/bias, f32 (16 lanes per row) ----
    {
        const int cg = lane & 15;
        const int rg = lane >> 4;
        #pragma unroll
        for (int g = 0; g < 2; ++g) {
            int r = wid * 8 + g * 4 + rg;
            int b = b0 + r;
            float aw = 0.f, ab = 0.f;
            #pragma unroll
            for (int c = 0; c < 16; ++c) {
                int off = cg * 4 + c * 64;
                f32x4 xv = *(const f32x4*)(x + (size_t)b * LL + off);
                f32x4 wv = *(const f32x4*)(fcw_w + off);
                f32x4 bv = *(const f32x4*)(fcb_w + off);
                #pragma unroll
                for (int j = 0; j < 4; ++j) {
                    aw += xv[j] * wv[j];
                    ab += xv[j] * bv[j];
                }
            }
            #pragma unroll
            for (int off = 1; off <= 8; off <<= 1) {
                aw += __shfl_xor(aw, off);
                ab += __shfl_xor(ab, off);
            }
            if (cg == 0) {
                float w  = tanhf(aw + fcw_b[0]) * 0.5f + 1.0f;
                float bi = tanhf(ab + fcb_b[0]) * 0.5f;
                w_s[r] = w; b_s[r] = bi;
                out[(size_t)BB * LL + b]      = w;
                out[(size_t)BB * LL + BB + b] = bi;
            }
        }
    }
    __syncthreads();

    // ---- Phase 3: out[b, n] = (att @ Wc)[b, n] * w[b] + bias[b] via bf16 MFMA ----
    {
        const int cg = lane & 15;   // A row / C col within 16-tile
        const int kg = lane >> 4;   // k-group
        bf16x8 a[2][2];
        #pragma unroll
        for (int rt = 0; rt < 2; ++rt) {
            int r = rt * 16 + cg;
            a[rt][0] = *(const bf16x8*)(att_s + r * 72 + kg * 8);
            a[rt][1] = *(const bf16x8*)(att_s + r * 72 + kg * 8 + 32);
        }
        float wreg[8], breg[8];
        #pragma unroll
        for (int rt = 0; rt < 2; ++rt)
            #pragma unroll
            for (int r4 = 0; r4 < 4; ++r4) {
                int row = rt * 16 + kg * 4 + r4;
                wreg[rt * 4 + r4] = w_s[row];
                breg[rt * 4 + r4] = b_s[row];
            }
        for (int nt = 0; nt < 16; ++nt) {
            int nc = wid * 256 + nt * 16;
            int n  = nc + cg;
            bf16x8 bf0 = *(const bf16x8*)(wc + n * 64 + kg * 8);
            bf16x8 bf1 = *(const bf16x8*)(wc + n * 64 + kg * 8 + 32);
            #pragma unroll
            for (int rt = 0; rt < 2; ++rt) {
                f32x4 acc = {0.f, 0.f, 0.f, 0.f};
                acc = __builtin_amdgcn_mfma_f32_16x16x32_bf16(a[rt][0], bf0, acc, 0, 0, 0);
                acc = __builtin_amdgcn_mfma_f32_16x16x32_bf16(a[rt][1], bf1, acc, 0, 0, 0);
                #pragma unroll
                for (int r4 = 0; r4 < 4; ++r4) {
                    int row = rt * 16 + kg * 4 + r4;
                    float v = acc[r4] * wreg[rt * 4 + r4] + breg[rt * 4 + r4];
                    out[(size_t)(b0 + row) * LL + n] = v;
                }
            }
        }
    }
}

extern "C" void kernel_launch(void* const* d_in, const int* in_sizes, int n_in,
                              void* d_out, int out_size, void* d_ws, size_t ws_size,
                              hipStream_t stream) {
    const float* x     = (const float*)d_in[0];
    const float* dv    = (const float*)d_in[1];
    // d_in[2] = conv_w: DEAD CODE in the reference (st is overwritten by st_mem)
    const float* convt = (const float*)d_in[3];
    const float* memW  = (const float*)d_in[4];
    const float* dateW = (const float*)d_in[5];
    const float* fcww  = (const float*)d_in[6];
    const float* fcwb  = (const float*)d_in[7];
    const float* fcbw  = (const float*)d_in[8];
    const float* fcbb  = (const float*)d_in[9];
    float* out = (float*)d_out;
    __bf16* wc = (__bf16*)d_ws;   // 1024*64 bf16 = 128 KB

    prep_wc<<<256, 256, 0, stream>>>(convt, memW, wc);
    memconv_main<<<BB / 32, 256, 0, stream>>>(x, dv, dateW, fcww, fcwb, fcbw, fcbb, wc, out);
}